// Round 1
// baseline (43.595 us; speedup 1.0000x reference)
//
#include <hip/hip_runtime.h>

// Closed form of the QLayer circuit:
//   RX(x_i)·RX(theta_i) on wire i, CNOT chain (0,1)..(6,7),(7,0), measure Z.
//   CNOTs permute basis states; bits are independent with
//   E[(-1)^{b_i}] = cos(x_i + theta_i) =: c_i.
//   Final bit w>=1 = b0^..^bw, final bit 0 = b1^..^b7, so
//     z[0] = c1*c2*...*c7,  z[w] = c0*c1*...*cw  (w >= 1).
// Then per token (B*S of them, 8 heads x 8 dims):
//   G = z z^T / sqrt(8); attn = softmax_rows(G); o = attn @ z;  y = o @ W^T + b.

__global__ __launch_bounds__(64)
void mhaq_fused(const float* __restrict__ x,
                const float* __restrict__ theta,
                const float* __restrict__ W,
                const float* __restrict__ bias,
                float* __restrict__ out,
                int n_tokens)
{
    __shared__ float Ws[64 * 64];
    __shared__ float bs[64];

    const int tid = threadIdx.x;

    // Stage W (16 KB) + bias into LDS, coalesced float4.
    {
        const float4* __restrict__ Wv = reinterpret_cast<const float4*>(W);
        float4* Wsv = reinterpret_cast<float4*>(Ws);
        #pragma unroll
        for (int i = 0; i < 16; ++i)
            Wsv[tid + i * 64] = Wv[tid + i * 64];
        if (tid < 16)
            reinterpret_cast<float4*>(bs)[tid] =
                reinterpret_cast<const float4*>(bias)[tid];
    }

    float th[8];
    #pragma unroll
    for (int w = 0; w < 8; ++w) th[w] = theta[w];  // uniform -> scalar loads

    __syncthreads();

    const int token = blockIdx.x * 64 + tid;
    if (token >= n_tokens) return;

    // ---- z[h*8+w]: closed-form circuit ----
    float z[64];
    {
        const float4* __restrict__ xp =
            reinterpret_cast<const float4*>(x + (size_t)token * 64);
        #pragma unroll
        for (int h = 0; h < 8; ++h) {
            float4 a  = xp[2 * h + 0];
            float4 bq = xp[2 * h + 1];
            float c0 = __cosf(a.x  + th[0]);
            float c1 = __cosf(a.y  + th[1]);
            float c2 = __cosf(a.z  + th[2]);
            float c3 = __cosf(a.w  + th[3]);
            float c4 = __cosf(bq.x + th[4]);
            float c5 = __cosf(bq.y + th[5]);
            float c6 = __cosf(bq.z + th[6]);
            float c7 = __cosf(bq.w + th[7]);
            float p1 = c0 * c1;
            float p2 = p1 * c2;
            float p3 = p2 * c3;
            float p4 = p3 * c4;
            float p5 = p4 * c5;
            float p6 = p5 * c6;
            float p7 = p6 * c7;
            float s6 = c6 * c7;
            float s5 = c5 * s6;
            float s4 = c4 * s5;
            float s3 = c3 * s4;
            float s2 = c2 * s3;
            float s1 = c1 * s2;   // c1*...*c7
            z[h * 8 + 0] = s1;
            z[h * 8 + 1] = p1;
            z[h * 8 + 2] = p2;
            z[h * 8 + 3] = p3;
            z[h * 8 + 4] = p4;
            z[h * 8 + 5] = p5;
            z[h * 8 + 6] = p6;
            z[h * 8 + 7] = p7;
        }
    }

    // ---- per-token 8x8 attention over heads ----
    float o[64];
    const float scale = 0.35355339059327373f;  // 1/sqrt(8)
    #pragma unroll
    for (int h = 0; h < 8; ++h) {
        float sc[8];
        float m = -4.0f;  // scores are in [-2.83, 2.83]
        #pragma unroll
        for (int t = 0; t < 8; ++t) {
            float s = 0.f;
            #pragma unroll
            for (int d = 0; d < 8; ++d)
                s = fmaf(z[h * 8 + d], z[t * 8 + d], s);
            s *= scale;
            sc[t] = s;
            m = fmaxf(m, s);
        }
        float sum = 0.f;
        #pragma unroll
        for (int t = 0; t < 8; ++t) {
            sc[t] = __expf(sc[t] - m);
            sum += sc[t];
        }
        float inv = 1.0f / sum;
        #pragma unroll
        for (int d = 0; d < 8; ++d) {
            float acc = 0.f;
            #pragma unroll
            for (int t = 0; t < 8; ++t)
                acc = fmaf(sc[t], z[t * 8 + d], acc);
            o[h * 8 + d] = acc * inv;
        }
    }

    // ---- y = o @ W^T + b (W broadcast from LDS, bank-conflict-free) ----
    float* __restrict__ yout = out + (size_t)token * 64;
    #pragma unroll 1
    for (int j = 0; j < 64; j += 4) {
        float a0 = bs[j + 0];
        float a1 = bs[j + 1];
        float a2 = bs[j + 2];
        float a3 = bs[j + 3];
        #pragma unroll
        for (int k = 0; k < 64; ++k) {
            float ok = o[k];
            a0 = fmaf(ok, Ws[(j + 0) * 64 + k], a0);
            a1 = fmaf(ok, Ws[(j + 1) * 64 + k], a1);
            a2 = fmaf(ok, Ws[(j + 2) * 64 + k], a2);
            a3 = fmaf(ok, Ws[(j + 3) * 64 + k], a3);
        }
        reinterpret_cast<float4*>(yout)[j >> 2] = make_float4(a0, a1, a2, a3);
    }
}

extern "C" void kernel_launch(void* const* d_in, const int* in_sizes, int n_in,
                              void* d_out, int out_size, void* d_ws, size_t ws_size,
                              hipStream_t stream)
{
    const float* x     = (const float*)d_in[0];
    const float* theta = (const float*)d_in[1];
    const float* W     = (const float*)d_in[2];
    const float* b     = (const float*)d_in[3];
    float* out         = (float*)d_out;

    const int n_tokens = in_sizes[0] / 64;       // B*S = 16384
    const int blocks   = (n_tokens + 63) / 64;   // 256 blocks x 1 wave
    mhaq_fused<<<blocks, 64, 0, stream>>>(x, theta, W, b, out, n_tokens);
}

// Round 2
// 11.397 us; speedup vs baseline: 3.8252x; 3.8252x over previous
//
#include <hip/hip_runtime.h>

// Closed form of the QLayer circuit (verified round 1, absmax 4.9e-4):
//   c_i = cos(x_i + theta_i); z[0] = c1..c7, z[w] = c0..cw (w>=1).
// Per token: G = z z^T / sqrt(8); attn = softmax rows; o = attn @ z;
//            y = o @ W^T + b.
//
// Parallelization: 8 threads per token (one per head).
//   phase 1: thread (tl,g) computes z for head g        -> zs[tl][g*8..]
//   phase 2: thread (tl,g) computes attention head g    -> os[tl][g*8..]
//   phase 3: thread (tl,g) computes output rows j=g*8+jj (j in [g*8, g*8+8))
// LDS: zs/os padded to stride 68 (4*tl mod 32 distinct -> conflict-free b128),
//      W stored float4 with XOR swizzle col' = k4 ^ (j>>3) so 8 lanes reading
//      8 distinct j-blocks at one logical k4 cover 8 distinct 4-bank groups.

#define TOK_PER_BLK 32

__global__ __launch_bounds__(256, 2)
void mhaq_fused2(const float* __restrict__ x,
                 const float* __restrict__ theta,
                 const float* __restrict__ W,
                 const float* __restrict__ bias,
                 float* __restrict__ out,
                 int n_tokens)
{
    __shared__ __align__(16) float Ws[64 * 64];          // swizzled, float4 units
    __shared__ __align__(16) float bs[64];
    __shared__ __align__(16) float zs[TOK_PER_BLK * 68]; // stride 68 (17 float4)
    __shared__ __align__(16) float os[TOK_PER_BLK * 68];

    const int tid = threadIdx.x;
    const int tl  = tid >> 3;   // token within block, 0..31
    const int g   = tid & 7;    // head index / output row-block
    const int token = blockIdx.x * TOK_PER_BLK + tl;
    const bool valid = token < n_tokens;

    // ---- stage W (16 KB) with XOR swizzle; coalesced global reads ----
    {
        const float4* __restrict__ Wv = reinterpret_cast<const float4*>(W);
        float4* Ws4 = reinterpret_cast<float4*>(Ws);
        #pragma unroll
        for (int i = 0; i < 4; ++i) {
            int idx = i * 256 + tid;            // 0..1023 (float4 index)
            int j   = idx >> 4;                 // W row
            int k4  = idx & 15;                 // logical float4 column
            Ws4[(j << 4) | (k4 ^ ((j >> 3) & 7))] = Wv[idx];
        }
        if (tid < 16)
            reinterpret_cast<float4*>(bs)[tid] =
                reinterpret_cast<const float4*>(bias)[tid];
    }

    // ---- phase 1: z for own head (8 cosf + prefix products) ----
    float zh[8];
    {
        float4 a = make_float4(0.f, 0.f, 0.f, 0.f);
        float4 b4 = make_float4(0.f, 0.f, 0.f, 0.f);
        if (valid) {
            const float4* __restrict__ xp =
                reinterpret_cast<const float4*>(x) + (size_t)token * 16 + g * 2;
            a = xp[0]; b4 = xp[1];
        }
        float c0 = __cosf(a.x  + theta[0]);
        float c1 = __cosf(a.y  + theta[1]);
        float c2 = __cosf(a.z  + theta[2]);
        float c3 = __cosf(a.w  + theta[3]);
        float c4 = __cosf(b4.x + theta[4]);
        float c5 = __cosf(b4.y + theta[5]);
        float c6 = __cosf(b4.z + theta[6]);
        float c7 = __cosf(b4.w + theta[7]);
        float p1 = c0 * c1;
        float p2 = p1 * c2;
        float p3 = p2 * c3;
        float p4 = p3 * c4;
        float p5 = p4 * c5;
        float p6 = p5 * c6;
        float p7 = p6 * c7;
        float s6 = c6 * c7;
        float s5 = c5 * s6;
        float s4 = c4 * s5;
        float s3 = c3 * s4;
        float s2 = c2 * s3;
        float s1 = c1 * s2;     // c1*...*c7
        zh[0] = s1; zh[1] = p1; zh[2] = p2; zh[3] = p3;
        zh[4] = p4; zh[5] = p5; zh[6] = p6; zh[7] = p7;

        float4* z4 = reinterpret_cast<float4*>(zs) + tl * 17 + g * 2;
        z4[0] = make_float4(zh[0], zh[1], zh[2], zh[3]);
        z4[1] = make_float4(zh[4], zh[5], zh[6], zh[7]);
    }
    __syncthreads();

    // ---- phase 2: attention head g ----
    {
        __align__(16) float zf[64];
        const float4* z4 = reinterpret_cast<const float4*>(zs) + tl * 17;
        #pragma unroll
        for (int k4 = 0; k4 < 16; ++k4)
            *reinterpret_cast<float4*>(&zf[4 * k4]) = z4[k4];

        const float scale = 0.35355339059327373f; // 1/sqrt(8)
        float sc[8];
        float m = -4.0f;                          // scores in [-2.83, 2.83]
        #pragma unroll
        for (int t = 0; t < 8; ++t) {
            float s = 0.f;
            #pragma unroll
            for (int d = 0; d < 8; ++d)
                s = fmaf(zh[d], zf[t * 8 + d], s);
            s *= scale;
            sc[t] = s;
            m = fmaxf(m, s);
        }
        float sum = 0.f;
        #pragma unroll
        for (int t = 0; t < 8; ++t) {
            sc[t] = __expf(sc[t] - m);
            sum += sc[t];
        }
        float inv = 1.0f / sum;

        float oh[8];
        #pragma unroll
        for (int d = 0; d < 8; ++d) {
            float acc = 0.f;
            #pragma unroll
            for (int t = 0; t < 8; ++t)
                acc = fmaf(sc[t], zf[t * 8 + d], acc);
            oh[d] = acc * inv;
        }
        float4* o4 = reinterpret_cast<float4*>(os) + tl * 17 + g * 2;
        o4[0] = make_float4(oh[0], oh[1], oh[2], oh[3]);
        o4[1] = make_float4(oh[4], oh[5], oh[6], oh[7]);
    }
    __syncthreads();

    // ---- phase 3: output rows j = g*8 + jj ----
    {
        __align__(16) float of[64];
        const float4* o4 = reinterpret_cast<const float4*>(os) + tl * 17;
        #pragma unroll
        for (int k4 = 0; k4 < 16; ++k4)
            *reinterpret_cast<float4*>(&of[4 * k4]) = o4[k4];

        float acc[8];
        #pragma unroll
        for (int jj = 0; jj < 8; ++jj)
            acc[jj] = bs[g * 8 + jj];

        const float4* Ws4 = reinterpret_cast<const float4*>(Ws);
        #pragma unroll
        for (int k4 = 0; k4 < 16; ++k4) {
            float4 ov = *reinterpret_cast<const float4*>(&of[4 * k4]);
            #pragma unroll
            for (int jj = 0; jj < 8; ++jj) {
                int j = g * 8 + jj;
                float4 w4 = Ws4[(j << 4) | (k4 ^ g)];   // unswizzle: (j>>3)&7 == g
                acc[jj] = fmaf(ov.x, w4.x, acc[jj]);
                acc[jj] = fmaf(ov.y, w4.y, acc[jj]);
                acc[jj] = fmaf(ov.z, w4.z, acc[jj]);
                acc[jj] = fmaf(ov.w, w4.w, acc[jj]);
            }
        }

        if (valid) {
            float4* yout = reinterpret_cast<float4*>(out) + (size_t)token * 16 + g * 2;
            yout[0] = make_float4(acc[0], acc[1], acc[2], acc[3]);
            yout[1] = make_float4(acc[4], acc[5], acc[6], acc[7]);
        }
    }
}

extern "C" void kernel_launch(void* const* d_in, const int* in_sizes, int n_in,
                              void* d_out, int out_size, void* d_ws, size_t ws_size,
                              hipStream_t stream)
{
    const float* x     = (const float*)d_in[0];
    const float* theta = (const float*)d_in[1];
    const float* W     = (const float*)d_in[2];
    const float* b     = (const float*)d_in[3];
    float* out         = (float*)d_out;

    const int n_tokens = in_sizes[0] / 64;                 // B*S = 16384
    const int blocks   = (n_tokens + TOK_PER_BLK - 1) / TOK_PER_BLK;  // 512
    mhaq_fused2<<<blocks, 256, 0, stream>>>(x, theta, W, b, out, n_tokens);
}

// Round 3
// 9.805 us; speedup vs baseline: 4.4462x; 1.1624x over previous
//
#include <hip/hip_runtime.h>

// Closed form of the QLayer circuit (verified r1/r2, absmax 4.9e-4):
//   c_i = cos(x_i + theta_i); z[0] = c1..c7, z[w] = c0..cw (w>=1).
// Per token: G = z z^T / sqrt(8); attn = softmax rows; o = attn @ z;
//            y = o @ W^T + b.
//
// R3: phase 3 (y = o @ W^T + b) moved to MFMA (16x16x32 bf16).
//   phases 1-2: 8 threads/token as before (measured fine).
//   phase 3: per wave: 1 M-tile (16 tokens) x 2 N-tiles (16 j each) x 2 K-steps
//            -> 4 MFMA, B-fragments (W) loaded once per wave, acc init = bias.
// Fragment maps (guide §3, m89-verified):
//   A: lane l -> A[m=l&15][k=(l>>4)*8+i]   (8 consecutive bf16 = 1 b128)
//   B: lane l -> B[k=(l>>4)*8+i][n=l&15]   (= row l&15 of W, consecutive k)
//   C: lane l, reg r -> [m=(l>>4)*4+r][n=l&15]

#define TOK_PER_BLK 32

typedef __attribute__((ext_vector_type(8))) short short8;
typedef __attribute__((ext_vector_type(4))) float f32x4;

__device__ inline unsigned short f2bf(float f) {
    unsigned u = __float_as_uint(f);
    u += 0x7FFF + ((u >> 16) & 1);          // RNE
    return (unsigned short)(u >> 16);
}

__global__ __launch_bounds__(256, 2)
void mhaq_fused3(const float* __restrict__ x,
                 const float* __restrict__ theta,
                 const float* __restrict__ W,
                 const float* __restrict__ bias,
                 float* __restrict__ out,
                 int n_tokens)
{
    __shared__ __align__(16) unsigned short Ws[64 * 72];        // bf16 W, pad 8
    __shared__ __align__(16) float          zs[TOK_PER_BLK * 68]; // f32 z, pad 4
    __shared__ __align__(16) unsigned short os[TOK_PER_BLK * 72]; // bf16 o, pad 8
    __shared__ float bs[64];

    const int tid = threadIdx.x;
    const int tl  = tid >> 3;     // token within block
    const int g   = tid & 7;      // head
    const int token = blockIdx.x * TOK_PER_BLK + tl;
    const bool valid = token < n_tokens;

    // ---- stage W (fp32 global -> bf16 LDS rows, pad 8) + bias ----
    {
        const float4* __restrict__ Wv = reinterpret_cast<const float4*>(W);
        #pragma unroll
        for (int i = 0; i < 4; ++i) {
            int idx = i * 256 + tid;     // float4 index 0..1023
            int j   = idx >> 4;          // W row
            int c4  = idx & 15;          // 4-float group within row
            float4 w = Wv[idx];
            *reinterpret_cast<ushort4*>(&Ws[j * 72 + c4 * 4]) =
                make_ushort4(f2bf(w.x), f2bf(w.y), f2bf(w.z), f2bf(w.w));
        }
        if (tid < 16)
            reinterpret_cast<float4*>(bs)[tid] =
                reinterpret_cast<const float4*>(bias)[tid];
    }

    // ---- phase 1: z for own head ----
    float zh[8];
    {
        float4 a  = make_float4(0.f, 0.f, 0.f, 0.f);
        float4 b4 = make_float4(0.f, 0.f, 0.f, 0.f);
        if (valid) {
            const float4* __restrict__ xp =
                reinterpret_cast<const float4*>(x) + (size_t)token * 16 + g * 2;
            a = xp[0]; b4 = xp[1];
        }
        float c0 = __cosf(a.x  + theta[0]);
        float c1 = __cosf(a.y  + theta[1]);
        float c2 = __cosf(a.z  + theta[2]);
        float c3 = __cosf(a.w  + theta[3]);
        float c4 = __cosf(b4.x + theta[4]);
        float c5 = __cosf(b4.y + theta[5]);
        float c6 = __cosf(b4.z + theta[6]);
        float c7 = __cosf(b4.w + theta[7]);
        float p1 = c0 * c1;
        float p2 = p1 * c2;
        float p3 = p2 * c3;
        float p4 = p3 * c4;
        float p5 = p4 * c5;
        float p6 = p5 * c6;
        float p7 = p6 * c7;
        float s6 = c6 * c7;
        float s5 = c5 * s6;
        float s4 = c4 * s5;
        float s3 = c3 * s4;
        float s2 = c2 * s3;
        float s1 = c1 * s2;     // c1*...*c7
        zh[0] = s1; zh[1] = p1; zh[2] = p2; zh[3] = p3;
        zh[4] = p4; zh[5] = p5; zh[6] = p6; zh[7] = p7;

        float4* z4 = reinterpret_cast<float4*>(zs + tl * 68 + g * 8);
        z4[0] = make_float4(zh[0], zh[1], zh[2], zh[3]);
        z4[1] = make_float4(zh[4], zh[5], zh[6], zh[7]);
    }
    __syncthreads();

    // ---- phase 2: attention head g; o -> bf16 LDS ----
    {
        __align__(16) float zf[64];
        const float* zrow = zs + tl * 68;
        #pragma unroll
        for (int k4 = 0; k4 < 16; ++k4)
            *reinterpret_cast<float4*>(&zf[4 * k4]) =
                *reinterpret_cast<const float4*>(&zrow[4 * k4]);

        const float scale = 0.35355339059327373f; // 1/sqrt(8)
        float sc[8];
        float m = -4.0f;                          // scores in [-2.83, 2.83]
        #pragma unroll
        for (int t = 0; t < 8; ++t) {
            float s = 0.f;
            #pragma unroll
            for (int d = 0; d < 8; ++d)
                s = fmaf(zh[d], zf[t * 8 + d], s);
            s *= scale;
            sc[t] = s;
            m = fmaxf(m, s);
        }
        float sum = 0.f;
        #pragma unroll
        for (int t = 0; t < 8; ++t) {
            sc[t] = __expf(sc[t] - m);
            sum += sc[t];
        }
        float inv = 1.0f / sum;

        unsigned short oh[8];
        #pragma unroll
        for (int d = 0; d < 8; ++d) {
            float acc = 0.f;
            #pragma unroll
            for (int t = 0; t < 8; ++t)
                acc = fmaf(sc[t], zf[t * 8 + d], acc);
            oh[d] = f2bf(acc * inv);
        }
        ushort4* o4 = reinterpret_cast<ushort4*>(&os[tl * 72 + g * 8]);
        o4[0] = make_ushort4(oh[0], oh[1], oh[2], oh[3]);
        o4[1] = make_ushort4(oh[4], oh[5], oh[6], oh[7]);
    }
    __syncthreads();

    // ---- phase 3: y = o @ W^T + b via MFMA ----
    {
        const int lane = tid & 63;
        const int wave = tid >> 6;   // 0..3
        const int mt   = wave & 1;   // M-tile: tokens mt*16..+16
        const int np   = wave >> 1;  // N-pair: j in [np*32, np*32+32)
        const int lr   = lane & 15;
        const int lg   = lane >> 4;  // 0..3

        short8 bfrag[2][2];
        #pragma unroll
        for (int nt = 0; nt < 2; ++nt) {
            int j = np * 32 + nt * 16 + lr;
            #pragma unroll
            for (int kt = 0; kt < 2; ++kt)
                bfrag[nt][kt] = *reinterpret_cast<const short8*>(
                    &Ws[j * 72 + kt * 32 + lg * 8]);
        }
        short8 afrag[2];
        #pragma unroll
        for (int kt = 0; kt < 2; ++kt)
            afrag[kt] = *reinterpret_cast<const short8*>(
                &os[(mt * 16 + lr) * 72 + kt * 32 + lg * 8]);

        #pragma unroll
        for (int nt = 0; nt < 2; ++nt) {
            int j = np * 32 + nt * 16 + lr;
            float bj = bs[j];
            f32x4 acc = {bj, bj, bj, bj};
            #pragma unroll
            for (int kt = 0; kt < 2; ++kt)
                acc = __builtin_amdgcn_mfma_f32_16x16x32_bf16(
                    afrag[kt], bfrag[nt][kt], acc, 0, 0, 0);
            #pragma unroll
            for (int r = 0; r < 4; ++r) {
                int trow = blockIdx.x * TOK_PER_BLK + mt * 16 + lg * 4 + r;
                if (trow < n_tokens)
                    out[(size_t)trow * 64 + j] = acc[r];
            }
        }
    }
}

extern "C" void kernel_launch(void* const* d_in, const int* in_sizes, int n_in,
                              void* d_out, int out_size, void* d_ws, size_t ws_size,
                              hipStream_t stream)
{
    const float* x     = (const float*)d_in[0];
    const float* theta = (const float*)d_in[1];
    const float* W     = (const float*)d_in[2];
    const float* b     = (const float*)d_in[3];
    float* out         = (float*)d_out;

    const int n_tokens = in_sizes[0] / 64;                            // 16384
    const int blocks   = (n_tokens + TOK_PER_BLK - 1) / TOK_PER_BLK;  // 512
    mhaq_fused3<<<blocks, 256, 0, stream>>>(x, theta, W, b, out, n_tokens);
}